// Round 15
// baseline (61.729 us; speedup 1.0000x reference)
//
#include <hip/hip_runtime.h>
#include <hip/hip_bf16.h>
#include <float.h>

#define B_ 64
#define C_ 512
#define Q_ 64
#define D_ 256

typedef _Float16 f16x8 __attribute__((ext_vector_type(8)));
typedef float f32x4 __attribute__((ext_vector_type(4)));

union U4H8 { uint4 u; f16x8 h; };
union UH2 { _Float16 h[2]; uint32_t u; };

__device__ __forceinline__ uint32_t packh2(float a, float b) {
  UH2 v; v.h[0] = (_Float16)a; v.h[1] = (_Float16)b; return v.u;
}

__device__ __forceinline__ float wred_sum(float v) {
#pragma unroll
  for (int off = 32; off > 0; off >>= 1) v += __shfl_xor(v, off, 64);
  return v;
}
__device__ __forceinline__ float wred_max(float v) {
#pragma unroll
  for (int off = 32; off > 0; off >>= 1) v = fmaxf(v, __shfl_xor(v, off, 64));
  return v;
}

// K1 (fallback only): out[row] = dot(src[row, 0:256], wgt[0:256])
__global__ __launch_bounds__(256) void k_rowdot(const float* __restrict__ src,
                                                const float* __restrict__ wgt,
                                                float* __restrict__ out, int nrows) {
  int wv = threadIdx.x >> 6, ln = threadIdx.x & 63;
  int row = blockIdx.x * 4 + wv;
  if (row >= nrows) return;
  float4 s4 = *(const float4*)(src + (size_t)row * D_ + 4 * ln);
  float4 w4 = *(const float4*)(wgt + 4 * ln);
  float p = s4.x * w4.x + s4.y * w4.y + s4.z * w4.z + s4.w * w4.w;
  p = wred_sum(p);
  if (ln == 0) out[row] = p;
}

// K0: prepack question into f16 images (qraw + qT layouts, XOR swizzle baked
// in) for linear global_load_lds staging in k_main; computes qwq.
// Parallelized: grid (B, 4) x 256 thr = 256 blocks.
__global__ __launch_bounds__(256) void k_prepack(const float* __restrict__ qst,
                                                 const float* __restrict__ w,
                                                 uint32_t* __restrict__ qraw_img,
                                                 uint32_t* __restrict__ qT_img,
                                                 float* __restrict__ qwq) {
  const int b = blockIdx.x;
  const int sub = blockIdx.y;      // 0..3
  const int t = threadIdx.x;
  const float* qb = qst + (size_t)b * Q_ * D_;
  // pass 1: qraw image — byte layout: q*512 + phys*16 + (jp&3)*4,
  // phys = (ch&~7)|((ch&7)^(q&7)), ch = jp>>2. This sub: idx in [sub*2048, +2048).
#pragma unroll
  for (int it = 0; it < 8; ++it) {
    int idx = sub * 2048 + it * 256 + t;
    int q = idx >> 7, jp = idx & 127;
    float2 v = *(const float2*)(qb + q * D_ + 2 * jp);
    int ch = jp >> 2;
    int phys = (ch & ~7) | ((ch & 7) ^ (q & 7));
    qraw_img[(size_t)b * 8192 + q * 128 + phys * 4 + (jp & 3)] = packh2(v.x, v.y);
  }
  // pass 2a: qT image — d = sub*64 + (t>>2); this thread does 2 qc-chunks.
  {
    int d = sub * 64 + (t >> 2);
    uint32_t* dst = qT_img + (size_t)b * 8192 + d * 32;
#pragma unroll
    for (int k = 0; k < 2; ++k) {
      int qc = (t & 3) * 2 + k;
      uint32_t tmp[4];
#pragma unroll
      for (int e = 0; e < 4; ++e) {
        int q0 = qc * 8 + e * 2;
        tmp[e] = packh2(qb[q0 * D_ + d], qb[(q0 + 1) * D_ + d]);
      }
      int pc = qc ^ (d & 7);
      *(uint4*)(dst + pc * 4) = uint4{tmp[0], tmp[1], tmp[2], tmp[3]};
    }
  }
  // pass 2b (sub 0 only): qwq[q] = dot(question[q], w_q); 4 lanes per q
  if (sub == 0) {
    int q = t >> 2, sl = t & 3;
    float p = 0.f;
#pragma unroll
    for (int i = 0; i < 16; ++i) {
      float4 v = *(const float4*)(qb + q * D_ + sl * 64 + i * 4);
      float4 ww = *(const float4*)(w + D_ + sl * 64 + i * 4);
      p += v.x * ww.x + v.y * ww.y + v.z * ww.z + v.w * ww.w;
    }
    p += __shfl_xor(p, 1, 64);
    p += __shfl_xor(p, 2, 64);
    if (sl == 0) qwq[b * Q_ + q] = p;
  }
}

// K2 (MFMA): r14 structure with rescheduled phases:
//   - qT staging issued AFTER barrier 1 (overlaps simT+softmax; drained by
//     barrier 2) instead of sitting in barrier-1's vmcnt(0) drain.
//   - g0 copy moved to the c2q epilogue (cvv already loads the full row),
//     removing 16 stores from barrier-1's drain.
// LDS = 32K(qraw) + 32K(qT) + 8K(P) + .5K = ~74 KB -> 2 blocks/CU.
template<int IMG>
__global__ __launch_bounds__(256, 2) void k_main(
    const float* __restrict__ ctx, const float* __restrict__ qst,
    const int* __restrict__ qmask, const float* __restrict__ w,
    const float* __restrict__ qwq_g,
    const uint32_t* __restrict__ qraw_img, const uint32_t* __restrict__ qT_img,
    float* __restrict__ g, float* __restrict__ simmax_g) {
  __shared__ __align__(16) ushort qraw[Q_ * D_];
  __shared__ __align__(16) ushort qT[D_ * Q_];
  __shared__ __align__(16) ushort pbuf[4][16 * Q_];
  __shared__ float qwq_l[Q_];
  __shared__ int   qml_l[Q_];

  const int bid = blockIdx.x;
  const int b = bid & 63;           // XCD-swizzle: same-b blocks share an XCD
  const int c0 = (bid >> 6) * 64;
  const int t = threadIdx.x;
  const int wv = t >> 6, ln = t & 63;
  const int lc = ln & 15;
  const int lg = ln >> 4;
  const int c0w = c0 + wv * 16;
  const float* qb = qst + (size_t)b * Q_ * D_;

  // ---- issue qraw image->LDS staging FIRST (hides under bfrag work) ----
  if constexpr (IMG) {
    const uint32_t* qr_src = qraw_img + (size_t)b * 8192;
#pragma unroll
    for (int i = 0; i < 8; ++i)
      __builtin_amdgcn_global_load_lds(
          (const __attribute__((address_space(1))) uint32_t*)(qr_src + i * 1024 + t * 4),
          (__attribute__((address_space(3))) uint32_t*)((uint32_t*)qraw + i * 1024 + t * 4),
          16, 0, 0);
  }

  // ---- B-frags: this wave's 16 ctx rows * w_m (f16) + fp32 cwc row-dot ----
  // (g0 copy deferred to the epilogue -> fewer stores in barrier-1 drain)
  f16x8 bfrag[8];
  float cwc_p = 0.f;
  const float* crow = ctx + ((size_t)b * C_ + c0w + lc) * D_;
#pragma unroll
  for (int kk = 0; kk < 8; ++kk) {
    int kb = kk * 32 + lg * 8;
    float4 cv0 = *(const float4*)(crow + kb);
    float4 cv1 = *(const float4*)(crow + kb + 4);
    float4 wc0 = *(const float4*)(w + kb);
    float4 wc1 = *(const float4*)(w + kb + 4);
    float4 wm0 = *(const float4*)(w + 2 * D_ + kb);
    float4 wm1 = *(const float4*)(w + 2 * D_ + kb + 4);
    cwc_p += cv0.x * wc0.x + cv0.y * wc0.y + cv0.z * wc0.z + cv0.w * wc0.w
           + cv1.x * wc1.x + cv1.y * wc1.y + cv1.z * wc1.z + cv1.w * wc1.w;
    bfrag[kk][0] = (_Float16)(cv0.x * wm0.x);
    bfrag[kk][1] = (_Float16)(cv0.y * wm0.y);
    bfrag[kk][2] = (_Float16)(cv0.z * wm0.z);
    bfrag[kk][3] = (_Float16)(cv0.w * wm0.w);
    bfrag[kk][4] = (_Float16)(cv1.x * wm1.x);
    bfrag[kk][5] = (_Float16)(cv1.y * wm1.y);
    bfrag[kk][6] = (_Float16)(cv1.z * wm1.z);
    bfrag[kk][7] = (_Float16)(cv1.w * wm1.w);
  }
  float cwc = cwc_p;
  cwc += __shfl_xor(cwc, 16, 64);
  cwc += __shfl_xor(cwc, 32, 64);

  if constexpr (!IMG) {
    // fallback: stage qraw (coalesced f32 re-read + pack), pre-barrier
#pragma unroll 4
    for (int it = 0; it < 32; ++it) {
      int idx = it * 256 + t;
      int q = idx >> 7, jp = idx & 127;
      float2 v = *(const float2*)(qb + q * D_ + 2 * jp);
      int ch = jp >> 2;
      int phys = (ch & ~7) | ((ch & 7) ^ (q & 7));
      *(uint32_t*)((char*)qraw + q * 512 + phys * 16 + (jp & 3) * 4) = packh2(v.x, v.y);
    }
  }
  if (t < Q_) { qwq_l[t] = qwq_g[b * Q_ + t]; qml_l[t] = qmask[b * Q_ + t]; }
  __syncthreads();   // barrier 1: qraw ready (drains qraw loads only)

  // ---- issue qT staging NOW: overlaps simT + softmax, drained by barrier 2 ----
  if constexpr (IMG) {
    const uint32_t* qt_src = qT_img + (size_t)b * 8192;
#pragma unroll
    for (int i = 0; i < 8; ++i)
      __builtin_amdgcn_global_load_lds(
          (const __attribute__((address_space(1))) uint32_t*)(qt_src + i * 1024 + t * 4),
          (__attribute__((address_space(3))) uint32_t*)((uint32_t*)qT + i * 1024 + t * 4),
          16, 0, 0);
  } else {
#pragma unroll 4
    for (int it = 0; it < 32; ++it) {
      int q = t & 63;
      int jp = (t >> 6) + 4 * it;
      float2 v = *(const float2*)(qb + q * D_ + 2 * jp);
      int d0 = 2 * jp, d1 = d0 + 1;
      UH2 h0; h0.h[0] = (_Float16)v.x;
      UH2 h1; h1.h[0] = (_Float16)v.y;
      *(ushort*)((char*)qT + d0 * 128 + (((q >> 3) ^ (d0 & 7)) << 4) + (q & 7) * 2) = (ushort)(h0.u & 0xffff);
      *(ushort*)((char*)qT + d1 * 128 + (((q >> 3) ^ (d1 & 7)) << 4) + (q & 7) * 2) = (ushort)(h1.u & 0xffff);
    }
  }

  // ---- simT[q, c] via MFMA: A = question rows (qraw LDS), B = (ctx*wm) ----
  f32x4 sacc[4];
#pragma unroll
  for (int tq = 0; tq < 4; ++tq) sacc[tq] = f32x4{0.f, 0.f, 0.f, 0.f};
#pragma unroll
  for (int tq = 0; tq < 4; ++tq) {
    int q = 16 * tq + lc;
#pragma unroll
    for (int kk = 0; kk < 8; ++kk) {
      int ch = lg + 4 * kk;
      int phys = (ch & ~7) | ((ch & 7) ^ (q & 7));
      U4H8 a; a.u = *(const uint4*)((const char*)qraw + q * 512 + phys * 16);
      sacc[tq] = __builtin_amdgcn_mfma_f32_16x16x32_f16(a.h, bfrag[kk], sacc[tq], 0, 0, 0);
    }
  }

  // ---- softmax over q (16 in-lane vals + xor16/xor32), P -> pbuf ----
  float vals[4][4];
  float rmax = -FLT_MAX;
#pragma unroll
  for (int tq = 0; tq < 4; ++tq) {
    float4 qw4 = *(const float4*)(qwq_l + 16 * tq + 4 * lg);
#pragma unroll
    for (int r = 0; r < 4; ++r) {
      float qv = (r == 0) ? qw4.x : (r == 1) ? qw4.y : (r == 2) ? qw4.z : qw4.w;
      vals[tq][r] = sacc[tq][r] + cwc + qv;
      rmax = fmaxf(rmax, vals[tq][r]);
    }
  }
  rmax = fmaxf(rmax, __shfl_xor(rmax, 16, 64));
  rmax = fmaxf(rmax, __shfl_xor(rmax, 32, 64));
  if (ln < 16) simmax_g[b * C_ + c0w + lc] = rmax;   // unmasked max (ref semantics)

  float mmax = -FLT_MAX;
#pragma unroll
  for (int tq = 0; tq < 4; ++tq) {
    int4 qm4 = *(const int4*)(qml_l + 16 * tq + 4 * lg);
#pragma unroll
    for (int r = 0; r < 4; ++r) {
      int m = (r == 0) ? qm4.x : (r == 1) ? qm4.y : (r == 2) ? qm4.z : qm4.w;
      vals[tq][r] = m ? vals[tq][r] : -FLT_MAX;
      mmax = fmaxf(mmax, vals[tq][r]);
    }
  }
  mmax = fmaxf(mmax, __shfl_xor(mmax, 16, 64));
  mmax = fmaxf(mmax, __shfl_xor(mmax, 32, 64));
  float esum = 0.f;
#pragma unroll
  for (int tq = 0; tq < 4; ++tq)
#pragma unroll
    for (int r = 0; r < 4; ++r) {
      vals[tq][r] = __expf(vals[tq][r] - mmax);      // masked -> exp(-huge) = 0
      esum += vals[tq][r];
    }
  esum += __shfl_xor(esum, 16, 64);
  esum += __shfl_xor(esum, 32, 64);
  float inv = 1.f / esum;
#pragma unroll
  for (int tq = 0; tq < 4; ++tq) {
    uint32_t p01 = packh2(vals[tq][0] * inv, vals[tq][1] * inv);
    uint32_t p23 = packh2(vals[tq][2] * inv, vals[tq][3] * inv);
    int qb4 = 16 * tq + 4 * lg;
    int phys = ((qb4 >> 3) ^ (lc & 7));
    char* dst = (char*)pbuf[wv] + lc * 128 + phys * 16 + (qb4 & 7) * 2;
    *(uint2*)dst = uint2{p01, p23};
  }
  __syncthreads();   // barrier 2: qT staged + P written (drains qT loads)

  // ---- c2qT[d, c] via MFMA: A = qT rows (d), B = P cols (c) ----
  // Epilogue also writes g0 = ctx copy from cvv (full row covered per wave).
  f16x8 pfragB[2];
#pragma unroll
  for (int ks = 0; ks < 2; ++ks) {
    int phys = (lg + 4 * ks) ^ (lc & 7);
    U4H8 a; a.u = *(const uint4*)((const char*)pbuf[wv] + lc * 128 + phys * 16);
    pfragB[ks] = a.h;
  }
  const float* crow2 = ctx + ((size_t)b * C_ + c0w + lc) * D_;
  float* grow = g + ((size_t)b * C_ + c0w + lc) * (4 * D_);
#pragma unroll 4
  for (int dt = 0; dt < 16; ++dt) {
    f32x4 acc = f32x4{0.f, 0.f, 0.f, 0.f};
#pragma unroll
    for (int ks = 0; ks < 2; ++ks) {
      int d = dt * 16 + lc;
      int phys = (lg + 4 * ks) ^ (d & 7);
      U4H8 aq; aq.u = *(const uint4*)((const char*)qT + d * 128 + phys * 16);
      acc = __builtin_amdgcn_mfma_f32_16x16x32_f16(aq.h, pfragB[ks], acc, 0, 0, 0);
    }
    int dcol = dt * 16 + 4 * lg;
    float4 cvv = *(const float4*)(crow2 + dcol);
    *(float4*)(grow + dcol) = cvv;                             // g[0:D] = ctx copy
    float4 c2qv{acc[0], acc[1], acc[2], acc[3]};
    *(float4*)(grow + D_ + dcol) = c2qv;                       // g[D:2D] = c2q
    float4 p2{cvv.x * c2qv.x, cvv.y * c2qv.y, cvv.z * c2qv.z, cvv.w * c2qv.w};
    *(float4*)(grow + 2 * D_ + dcol) = p2;                     // g[2D:3D] = ctx*c2q
  }
}

// K3: fused per-batch masked softmax over sim_max + partial q2c
__global__ __launch_bounds__(256) void k_q2c_bs(const float* __restrict__ ctx,
                                                const float* __restrict__ simmax,
                                                const int* __restrict__ cmask,
                                                float* __restrict__ part) {
  int b = blockIdx.x, ch = blockIdx.y, t = threadIdx.x;
  int wv = t >> 6, ln = t & 63;
  __shared__ float bls[C_];
  __shared__ float sred[4];
  __shared__ float ssum[4];
  float v0 = simmax[b * C_ + t], v1 = simmax[b * C_ + 256 + t];
  if (!cmask[b * C_ + t]) v0 = -FLT_MAX;
  if (!cmask[b * C_ + 256 + t]) v1 = -FLT_MAX;
  float mx = wred_max(fmaxf(v0, v1));
  if (ln == 0) sred[wv] = mx;
  __syncthreads();
  float bm = fmaxf(fmaxf(sred[0], sred[1]), fmaxf(sred[2], sred[3]));
  float e0 = __expf(v0 - bm), e1 = __expf(v1 - bm);
  float ps = wred_sum(e0 + e1);
  if (ln == 0) ssum[wv] = ps;
  __syncthreads();
  float bs = ssum[0] + ssum[1] + ssum[2] + ssum[3];
  float invbs = 1.f / bs;
  bls[t] = e0 * invbs;
  bls[256 + t] = e1 * invbs;
  __syncthreads();
  float acc = 0.f;
  int cbeg = ch * 64;
#pragma unroll 4
  for (int c = cbeg; c < cbeg + 64; ++c)
    acc += bls[c] * ctx[((size_t)b * C_ + c) * D_ + t];
  part[((size_t)b * 8 + ch) * D_ + t] = acc;
}

// K4: reduce partials (redundant per block, L2-hot) -> q2c in LDS, then
// stream 64 ctx rows writing g[3D:4D] = ctx * q2c with float4.
__global__ __launch_bounds__(256) void k_g3q(const float* __restrict__ ctx,
                                             const float* __restrict__ part,
                                             float* __restrict__ g) {
  int b = blockIdx.x, ch = blockIdx.y, t = threadIdx.x;
  __shared__ float q2c_l[D_];
  float s = 0.f;
#pragma unroll
  for (int k = 0; k < 8; ++k) s += part[((size_t)b * 8 + k) * D_ + t];
  q2c_l[t] = s;
  __syncthreads();
  int d4 = t & 63;
  int ro = t >> 6;
  float4 qv = *(const float4*)(q2c_l + 4 * d4);
#pragma unroll 4
  for (int it = 0; it < 16; ++it) {
    int c = ch * 64 + it * 4 + ro;
    float4 cv = *(const float4*)(ctx + ((size_t)b * C_ + c) * D_ + 4 * d4);
    float4 o{cv.x * qv.x, cv.y * qv.y, cv.z * qv.z, cv.w * qv.w};
    *(float4*)(g + ((size_t)b * C_ + c) * (4 * D_) + 3 * D_ + 4 * d4) = o;
  }
}

extern "C" void kernel_launch(void* const* d_in, const int* in_sizes, int n_in,
                              void* d_out, int out_size, void* d_ws, size_t ws_size,
                              hipStream_t stream) {
  const float* ctx   = (const float*)d_in[0];
  const float* qst   = (const float*)d_in[1];
  const int*   cmask = (const int*)d_in[2];
  const int*   qmask = (const int*)d_in[3];
  const float* w     = (const float*)d_in[4];
  float* g  = (float*)d_out;
  float* ws = (float*)d_ws;

  float*    qwq      = ws;             // B*Q   = 4096 floats
  float*    simmax   = ws + 4096;      // B*C   = 32768
  float*    part     = ws + 36864;     // B*8*D = 131072
  uint32_t* qraw_img = (uint32_t*)(ws + 167936);   // 524288 u32 (2 MB)
  uint32_t* qT_img   = (uint32_t*)(ws + 692224);   // 524288 u32 (2 MB)
  const size_t need_bytes = (size_t)(692224 + 524288) * 4;   // ~4.64 MB

  if (ws_size >= need_bytes) {
    k_prepack<<<dim3(B_, 4), 256, 0, stream>>>(qst, w, qraw_img, qT_img, qwq);
    k_main<1><<<dim3(512), 256, 0, stream>>>(ctx, qst, qmask, w, qwq,
                                             qraw_img, qT_img, g, simmax);
  } else {
    k_rowdot<<<dim3(B_ * Q_ / 4), 256, 0, stream>>>(qst, w + D_, qwq, B_ * Q_);
    k_main<0><<<dim3(512), 256, 0, stream>>>(ctx, qst, qmask, w, qwq,
                                             qraw_img, qT_img, g, simmax);
  }
  k_q2c_bs<<<dim3(B_, 8), 256, 0, stream>>>(ctx, simmax, cmask, part);
  k_g3q<<<dim3(B_, 8), 256, 0, stream>>>(ctx, part, g);
}

// Round 16
// 60.677 us; speedup vs baseline: 1.0173x; 1.0173x over previous
//
#include <hip/hip_runtime.h>
#include <hip/hip_bf16.h>
#include <float.h>

#define B_ 64
#define C_ 512
#define Q_ 64
#define D_ 256

typedef _Float16 f16x8 __attribute__((ext_vector_type(8)));
typedef float f32x4 __attribute__((ext_vector_type(4)));

union U4H8 { uint4 u; f16x8 h; };
union UH2 { _Float16 h[2]; uint32_t u; };

__device__ __forceinline__ uint32_t packh2(float a, float b) {
  UH2 v; v.h[0] = (_Float16)a; v.h[1] = (_Float16)b; return v.u;
}

__device__ __forceinline__ float wred_sum(float v) {
#pragma unroll
  for (int off = 32; off > 0; off >>= 1) v += __shfl_xor(v, off, 64);
  return v;
}
__device__ __forceinline__ float wred_max(float v) {
#pragma unroll
  for (int off = 32; off > 0; off >>= 1) v = fmaxf(v, __shfl_xor(v, off, 64));
  return v;
}

// ---------- fallback-only kernels (r14 path) ----------
__global__ __launch_bounds__(256) void k_rowdot(const float* __restrict__ src,
                                                const float* __restrict__ wgt,
                                                float* __restrict__ out, int nrows) {
  int wv = threadIdx.x >> 6, ln = threadIdx.x & 63;
  int row = blockIdx.x * 4 + wv;
  if (row >= nrows) return;
  float4 s4 = *(const float4*)(src + (size_t)row * D_ + 4 * ln);
  float4 w4 = *(const float4*)(wgt + 4 * ln);
  float p = s4.x * w4.x + s4.y * w4.y + s4.z * w4.z + s4.w * w4.w;
  p = wred_sum(p);
  if (ln == 0) out[row] = p;
}

// K0: prepack question into f16 images (qraw + qT layouts, XOR swizzle baked
// in) for linear global_load_lds staging; computes qwq. grid (B,4) x 256.
__global__ __launch_bounds__(256) void k_prepack(const float* __restrict__ qst,
                                                 const float* __restrict__ w,
                                                 uint32_t* __restrict__ qraw_img,
                                                 uint32_t* __restrict__ qT_img,
                                                 float* __restrict__ qwq) {
  const int b = blockIdx.x;
  const int sub = blockIdx.y;      // 0..3
  const int t = threadIdx.x;
  const float* qb = qst + (size_t)b * Q_ * D_;
#pragma unroll
  for (int it = 0; it < 8; ++it) {
    int idx = sub * 2048 + it * 256 + t;
    int q = idx >> 7, jp = idx & 127;
    float2 v = *(const float2*)(qb + q * D_ + 2 * jp);
    int ch = jp >> 2;
    int phys = (ch & ~7) | ((ch & 7) ^ (q & 7));
    qraw_img[(size_t)b * 8192 + q * 128 + phys * 4 + (jp & 3)] = packh2(v.x, v.y);
  }
  {
    int d = sub * 64 + (t >> 2);
    uint32_t* dst = qT_img + (size_t)b * 8192 + d * 32;
#pragma unroll
    for (int k = 0; k < 2; ++k) {
      int qc = (t & 3) * 2 + k;
      uint32_t tmp[4];
#pragma unroll
      for (int e = 0; e < 4; ++e) {
        int q0 = qc * 8 + e * 2;
        tmp[e] = packh2(qb[q0 * D_ + d], qb[(q0 + 1) * D_ + d]);
      }
      int pc = qc ^ (d & 7);
      *(uint4*)(dst + pc * 4) = uint4{tmp[0], tmp[1], tmp[2], tmp[3]};
    }
  }
  if (sub == 0) {
    int q = t >> 2, sl = t & 3;
    float p = 0.f;
#pragma unroll
    for (int i = 0; i < 16; ++i) {
      float4 v = *(const float4*)(qb + q * D_ + sl * 64 + i * 4);
      float4 ww = *(const float4*)(w + D_ + sl * 64 + i * 4);
      p += v.x * ww.x + v.y * ww.y + v.z * ww.z + v.w * ww.w;
    }
    p += __shfl_xor(p, 1, 64);
    p += __shfl_xor(p, 2, 64);
    if (sl == 0) qwq[b * Q_ + q] = p;
  }
}

// KA: sim half. LDS = 32K(qraw) + .5K -> 4 blocks/CU (16 waves/CU).
// simT = mfma(qraw, ctx*wm); softmax; P -> LINEAR global image [c][q] f16
// (XOR swizzle unnecessary in global); simmax out. No epilogue, no qT.
__global__ __launch_bounds__(256, 4) void k_sim(
    const float* __restrict__ ctx, const int* __restrict__ qmask,
    const float* __restrict__ w, const float* __restrict__ qwq_g,
    const uint32_t* __restrict__ qraw_img,
    ushort* __restrict__ P_img, float* __restrict__ simmax_g) {
  __shared__ __align__(16) ushort qraw[Q_ * D_];
  __shared__ float qwq_l[Q_];
  __shared__ int   qml_l[Q_];

  const int bid = blockIdx.x;
  const int b = bid & 63;           // XCD-swizzle
  const int c0 = (bid >> 6) * 64;
  const int t = threadIdx.x;
  const int wv = t >> 6, ln = t & 63;
  const int lc = ln & 15;
  const int lg = ln >> 4;
  const int c0w = c0 + wv * 16;

  // ---- qraw image -> LDS (linear, width-16), issued first ----
  {
    const uint32_t* qr_src = qraw_img + (size_t)b * 8192;
#pragma unroll
    for (int i = 0; i < 8; ++i)
      __builtin_amdgcn_global_load_lds(
          (const __attribute__((address_space(1))) uint32_t*)(qr_src + i * 1024 + t * 4),
          (__attribute__((address_space(3))) uint32_t*)((uint32_t*)qraw + i * 1024 + t * 4),
          16, 0, 0);
  }

  // ---- B-frags: 16 ctx rows * w_m (f16) + fp32 cwc row-dot ----
  f16x8 bfrag[8];
  float cwc_p = 0.f;
  const float* crow = ctx + ((size_t)b * C_ + c0w + lc) * D_;
#pragma unroll
  for (int kk = 0; kk < 8; ++kk) {
    int kb = kk * 32 + lg * 8;
    float4 cv0 = *(const float4*)(crow + kb);
    float4 cv1 = *(const float4*)(crow + kb + 4);
    float4 wc0 = *(const float4*)(w + kb);
    float4 wc1 = *(const float4*)(w + kb + 4);
    float4 wm0 = *(const float4*)(w + 2 * D_ + kb);
    float4 wm1 = *(const float4*)(w + 2 * D_ + kb + 4);
    cwc_p += cv0.x * wc0.x + cv0.y * wc0.y + cv0.z * wc0.z + cv0.w * wc0.w
           + cv1.x * wc1.x + cv1.y * wc1.y + cv1.z * wc1.z + cv1.w * wc1.w;
    bfrag[kk][0] = (_Float16)(cv0.x * wm0.x);
    bfrag[kk][1] = (_Float16)(cv0.y * wm0.y);
    bfrag[kk][2] = (_Float16)(cv0.z * wm0.z);
    bfrag[kk][3] = (_Float16)(cv0.w * wm0.w);
    bfrag[kk][4] = (_Float16)(cv1.x * wm1.x);
    bfrag[kk][5] = (_Float16)(cv1.y * wm1.y);
    bfrag[kk][6] = (_Float16)(cv1.z * wm1.z);
    bfrag[kk][7] = (_Float16)(cv1.w * wm1.w);
  }
  float cwc = cwc_p;
  cwc += __shfl_xor(cwc, 16, 64);
  cwc += __shfl_xor(cwc, 32, 64);

  if (t < Q_) { qwq_l[t] = qwq_g[b * Q_ + t]; qml_l[t] = qmask[b * Q_ + t]; }
  __syncthreads();

  // ---- simT[q, c] via MFMA ----
  f32x4 sacc[4];
#pragma unroll
  for (int tq = 0; tq < 4; ++tq) sacc[tq] = f32x4{0.f, 0.f, 0.f, 0.f};
#pragma unroll
  for (int tq = 0; tq < 4; ++tq) {
    int q = 16 * tq + lc;
#pragma unroll
    for (int kk = 0; kk < 8; ++kk) {
      int ch = lg + 4 * kk;
      int phys = (ch & ~7) | ((ch & 7) ^ (q & 7));
      U4H8 a; a.u = *(const uint4*)((const char*)qraw + q * 512 + phys * 16);
      sacc[tq] = __builtin_amdgcn_mfma_f32_16x16x32_f16(a.h, bfrag[kk], sacc[tq], 0, 0, 0);
    }
  }

  // ---- softmax over q ----
  float vals[4][4];
  float rmax = -FLT_MAX;
#pragma unroll
  for (int tq = 0; tq < 4; ++tq) {
    float4 qw4 = *(const float4*)(qwq_l + 16 * tq + 4 * lg);
#pragma unroll
    for (int r = 0; r < 4; ++r) {
      float qv = (r == 0) ? qw4.x : (r == 1) ? qw4.y : (r == 2) ? qw4.z : qw4.w;
      vals[tq][r] = sacc[tq][r] + cwc + qv;
      rmax = fmaxf(rmax, vals[tq][r]);
    }
  }
  rmax = fmaxf(rmax, __shfl_xor(rmax, 16, 64));
  rmax = fmaxf(rmax, __shfl_xor(rmax, 32, 64));
  if (ln < 16) simmax_g[b * C_ + c0w + lc] = rmax;   // unmasked max (ref semantics)

  float mmax = -FLT_MAX;
#pragma unroll
  for (int tq = 0; tq < 4; ++tq) {
    int4 qm4 = *(const int4*)(qml_l + 16 * tq + 4 * lg);
#pragma unroll
    for (int r = 0; r < 4; ++r) {
      int m = (r == 0) ? qm4.x : (r == 1) ? qm4.y : (r == 2) ? qm4.z : qm4.w;
      vals[tq][r] = m ? vals[tq][r] : -FLT_MAX;
      mmax = fmaxf(mmax, vals[tq][r]);
    }
  }
  mmax = fmaxf(mmax, __shfl_xor(mmax, 16, 64));
  mmax = fmaxf(mmax, __shfl_xor(mmax, 32, 64));
  float esum = 0.f;
#pragma unroll
  for (int tq = 0; tq < 4; ++tq)
#pragma unroll
    for (int r = 0; r < 4; ++r) {
      vals[tq][r] = __expf(vals[tq][r] - mmax);      // masked -> exp(-huge) = 0
      esum += vals[tq][r];
    }
  esum += __shfl_xor(esum, 16, 64);
  esum += __shfl_xor(esum, 32, 64);
  float inv = 1.f / esum;
  // ---- P -> linear global image [c(16 rows x 128B)][q] per (bid, wave) ----
  char* pdst = (char*)(P_img + ((size_t)bid * 4 + wv) * 1024);
#pragma unroll
  for (int tq = 0; tq < 4; ++tq) {
    uint32_t p01 = packh2(vals[tq][0] * inv, vals[tq][1] * inv);
    uint32_t p23 = packh2(vals[tq][2] * inv, vals[tq][3] * inv);
    int qb4 = 16 * tq + 4 * lg;
    *(uint2*)(pdst + lc * 128 + qb4 * 2) = uint2{p01, p23};
  }
}

// KB: c2q half. LDS = 32K(qT) + 1K(q2c) -> 4 blocks/CU.
// Stage qT via global_load_lds; pfragB direct from P_img (L2-hot);
// reduce part->q2c in LDS; c2q MFMA; epilogue writes g0,g1,g2,g3.
__global__ __launch_bounds__(256, 4) void k_c2q(
    const float* __restrict__ ctx, const uint32_t* __restrict__ qT_img,
    const ushort* __restrict__ P_img, const float* __restrict__ part,
    float* __restrict__ g) {
  __shared__ __align__(16) ushort qT[D_ * Q_];
  __shared__ float q2c_l[D_];

  const int bid = blockIdx.x;
  const int b = bid & 63;
  const int c0 = (bid >> 6) * 64;
  const int t = threadIdx.x;
  const int wv = t >> 6, ln = t & 63;
  const int lc = ln & 15;
  const int lg = ln >> 4;
  const int c0w = c0 + wv * 16;

  // ---- qT image -> LDS (linear, width-16) ----
  {
    const uint32_t* qt_src = qT_img + (size_t)b * 8192;
#pragma unroll
    for (int i = 0; i < 8; ++i)
      __builtin_amdgcn_global_load_lds(
          (const __attribute__((address_space(1))) uint32_t*)(qt_src + i * 1024 + t * 4),
          (__attribute__((address_space(3))) uint32_t*)((uint32_t*)qT + i * 1024 + t * 4),
          16, 0, 0);
  }
  // ---- pfragB: direct global reads (linear [c][q] image; chunk lg+4ks) ----
  const char* psrc = (const char*)(P_img + ((size_t)bid * 4 + wv) * 1024);
  U4H8 pf0, pf1;
  pf0.u = *(const uint4*)(psrc + lc * 128 + lg * 16);        // ks=0
  pf1.u = *(const uint4*)(psrc + lc * 128 + lg * 16 + 64);   // ks=1
  // ---- reduce partials -> q2c (fixed order, L2-hot) ----
  {
    float s = 0.f;
#pragma unroll
    for (int k = 0; k < 8; ++k) s += part[((size_t)b * 8 + k) * D_ + t];
    q2c_l[t] = s;
  }
  __syncthreads();   // drains qT loads + q2c writes

  // ---- c2qT[d, c] via MFMA + full epilogue ----
  const float* crow2 = ctx + ((size_t)b * C_ + c0w + lc) * D_;
  float* grow = g + ((size_t)b * C_ + c0w + lc) * (4 * D_);
#pragma unroll 4
  for (int dt = 0; dt < 16; ++dt) {
    f32x4 acc = f32x4{0.f, 0.f, 0.f, 0.f};
    {
      int d = dt * 16 + lc;
      int phys0 = lg ^ (d & 7);
      int phys1 = (lg + 4) ^ (d & 7);
      U4H8 aq0; aq0.u = *(const uint4*)((const char*)qT + d * 128 + phys0 * 16);
      U4H8 aq1; aq1.u = *(const uint4*)((const char*)qT + d * 128 + phys1 * 16);
      acc = __builtin_amdgcn_mfma_f32_16x16x32_f16(aq0.h, pf0.h, acc, 0, 0, 0);
      acc = __builtin_amdgcn_mfma_f32_16x16x32_f16(aq1.h, pf1.h, acc, 0, 0, 0);
    }
    int dcol = dt * 16 + 4 * lg;
    float4 cvv = *(const float4*)(crow2 + dcol);
    float4 q4 = *(const float4*)(q2c_l + dcol);
    *(float4*)(grow + dcol) = cvv;                             // g[0:D] = ctx
    float4 c2qv{acc[0], acc[1], acc[2], acc[3]};
    *(float4*)(grow + D_ + dcol) = c2qv;                       // g[D:2D] = c2q
    float4 p2{cvv.x * c2qv.x, cvv.y * c2qv.y, cvv.z * c2qv.z, cvv.w * c2qv.w};
    *(float4*)(grow + 2 * D_ + dcol) = p2;                     // g[2D:3D]
    float4 p3{cvv.x * q4.x, cvv.y * q4.y, cvv.z * q4.z, cvv.w * q4.w};
    *(float4*)(grow + 3 * D_ + dcol) = p3;                     // g[3D:4D]
  }
}

// K3: fused per-batch masked softmax over sim_max + partial q2c
__global__ __launch_bounds__(256) void k_q2c_bs(const float* __restrict__ ctx,
                                                const float* __restrict__ simmax,
                                                const int* __restrict__ cmask,
                                                float* __restrict__ part) {
  int b = blockIdx.x, ch = blockIdx.y, t = threadIdx.x;
  int wv = t >> 6, ln = t & 63;
  __shared__ float bls[C_];
  __shared__ float sred[4];
  __shared__ float ssum[4];
  float v0 = simmax[b * C_ + t], v1 = simmax[b * C_ + 256 + t];
  if (!cmask[b * C_ + t]) v0 = -FLT_MAX;
  if (!cmask[b * C_ + 256 + t]) v1 = -FLT_MAX;
  float mx = wred_max(fmaxf(v0, v1));
  if (ln == 0) sred[wv] = mx;
  __syncthreads();
  float bm = fmaxf(fmaxf(sred[0], sred[1]), fmaxf(sred[2], sred[3]));
  float e0 = __expf(v0 - bm), e1 = __expf(v1 - bm);
  float ps = wred_sum(e0 + e1);
  if (ln == 0) ssum[wv] = ps;
  __syncthreads();
  float bs = ssum[0] + ssum[1] + ssum[2] + ssum[3];
  float invbs = 1.f / bs;
  bls[t] = e0 * invbs;
  bls[256 + t] = e1 * invbs;
  __syncthreads();
  float acc = 0.f;
  int cbeg = ch * 64;
#pragma unroll 4
  for (int c = cbeg; c < cbeg + 64; ++c)
    acc += bls[c] * ctx[((size_t)b * C_ + c) * D_ + t];
  part[((size_t)b * 8 + ch) * D_ + t] = acc;
}

// ---------- fallback k_main (r14, IMG=0 only) ----------
__global__ __launch_bounds__(256, 2) void k_main_fb(
    const float* __restrict__ ctx, const float* __restrict__ qst,
    const int* __restrict__ qmask, const float* __restrict__ w,
    const float* __restrict__ qwq_g, float* __restrict__ g,
    float* __restrict__ simmax_g) {
  __shared__ __align__(16) ushort qraw[Q_ * D_];
  __shared__ __align__(16) ushort qT[D_ * Q_];
  __shared__ __align__(16) ushort pbuf[4][16 * Q_];
  __shared__ float qwq_l[Q_];
  __shared__ int   qml_l[Q_];

  const int bid = blockIdx.x;
  const int b = bid & 63;
  const int c0 = (bid >> 6) * 64;
  const int t = threadIdx.x;
  const int wv = t >> 6, ln = t & 63;
  const int lc = ln & 15;
  const int lg = ln >> 4;
  const int c0w = c0 + wv * 16;
  const float* qb = qst + (size_t)b * Q_ * D_;

  f16x8 bfrag[8];
  float cwc_p = 0.f;
  const float* crow = ctx + ((size_t)b * C_ + c0w + lc) * D_;
  float* grow0 = g + ((size_t)b * C_ + c0w + lc) * (4 * D_);
#pragma unroll
  for (int kk = 0; kk < 8; ++kk) {
    int kb = kk * 32 + lg * 8;
    float4 cv0 = *(const float4*)(crow + kb);
    float4 cv1 = *(const float4*)(crow + kb + 4);
    float4 wc0 = *(const float4*)(w + kb);
    float4 wc1 = *(const float4*)(w + kb + 4);
    float4 wm0 = *(const float4*)(w + 2 * D_ + kb);
    float4 wm1 = *(const float4*)(w + 2 * D_ + kb + 4);
    cwc_p += cv0.x * wc0.x + cv0.y * wc0.y + cv0.z * wc0.z + cv0.w * wc0.w
           + cv1.x * wc1.x + cv1.y * wc1.y + cv1.z * wc1.z + cv1.w * wc1.w;
    bfrag[kk][0] = (_Float16)(cv0.x * wm0.x);
    bfrag[kk][1] = (_Float16)(cv0.y * wm0.y);
    bfrag[kk][2] = (_Float16)(cv0.z * wm0.z);
    bfrag[kk][3] = (_Float16)(cv0.w * wm0.w);
    bfrag[kk][4] = (_Float16)(cv1.x * wm1.x);
    bfrag[kk][5] = (_Float16)(cv1.y * wm1.y);
    bfrag[kk][6] = (_Float16)(cv1.z * wm1.z);
    bfrag[kk][7] = (_Float16)(cv1.w * wm1.w);
    *(float4*)(grow0 + kb) = cv0;
    *(float4*)(grow0 + kb + 4) = cv1;
  }
  float cwc = cwc_p;
  cwc += __shfl_xor(cwc, 16, 64);
  cwc += __shfl_xor(cwc, 32, 64);

#pragma unroll 4
  for (int it = 0; it < 32; ++it) {
    int idx = it * 256 + t;
    int q = idx >> 7, jp = idx & 127;
    float2 v = *(const float2*)(qb + q * D_ + 2 * jp);
    int ch = jp >> 2;
    int phys = (ch & ~7) | ((ch & 7) ^ (q & 7));
    *(uint32_t*)((char*)qraw + q * 512 + phys * 16 + (jp & 3) * 4) = packh2(v.x, v.y);
  }
#pragma unroll 4
  for (int it = 0; it < 32; ++it) {
    int q = t & 63;
    int jp = (t >> 6) + 4 * it;
    float2 v = *(const float2*)(qb + q * D_ + 2 * jp);
    int d0 = 2 * jp, d1 = d0 + 1;
    UH2 h0; h0.h[0] = (_Float16)v.x;
    UH2 h1; h1.h[0] = (_Float16)v.y;
    *(ushort*)((char*)qT + d0 * 128 + (((q >> 3) ^ (d0 & 7)) << 4) + (q & 7) * 2) = (ushort)(h0.u & 0xffff);
    *(ushort*)((char*)qT + d1 * 128 + (((q >> 3) ^ (d1 & 7)) << 4) + (q & 7) * 2) = (ushort)(h1.u & 0xffff);
  }
  if (t < Q_) { qwq_l[t] = qwq_g[b * Q_ + t]; qml_l[t] = qmask[b * Q_ + t]; }
  __syncthreads();

  f32x4 sacc[4];
#pragma unroll
  for (int tq = 0; tq < 4; ++tq) sacc[tq] = f32x4{0.f, 0.f, 0.f, 0.f};
#pragma unroll
  for (int tq = 0; tq < 4; ++tq) {
    int q = 16 * tq + lc;
#pragma unroll
    for (int kk = 0; kk < 8; ++kk) {
      int ch = lg + 4 * kk;
      int phys = (ch & ~7) | ((ch & 7) ^ (q & 7));
      U4H8 a; a.u = *(const uint4*)((const char*)qraw + q * 512 + phys * 16);
      sacc[tq] = __builtin_amdgcn_mfma_f32_16x16x32_f16(a.h, bfrag[kk], sacc[tq], 0, 0, 0);
    }
  }
  float vals[4][4];
  float rmax = -FLT_MAX;
#pragma unroll
  for (int tq = 0; tq < 4; ++tq) {
    float4 qw4 = *(const float4*)(qwq_l + 16 * tq + 4 * lg);
#pragma unroll
    for (int r = 0; r < 4; ++r) {
      float qv = (r == 0) ? qw4.x : (r == 1) ? qw4.y : (r == 2) ? qw4.z : qw4.w;
      vals[tq][r] = sacc[tq][r] + cwc + qv;
      rmax = fmaxf(rmax, vals[tq][r]);
    }
  }
  rmax = fmaxf(rmax, __shfl_xor(rmax, 16, 64));
  rmax = fmaxf(rmax, __shfl_xor(rmax, 32, 64));
  if (ln < 16) simmax_g[b * C_ + c0w + lc] = rmax;
  float mmax = -FLT_MAX;
#pragma unroll
  for (int tq = 0; tq < 4; ++tq) {
    int4 qm4 = *(const int4*)(qml_l + 16 * tq + 4 * lg);
#pragma unroll
    for (int r = 0; r < 4; ++r) {
      int m = (r == 0) ? qm4.x : (r == 1) ? qm4.y : (r == 2) ? qm4.z : qm4.w;
      vals[tq][r] = m ? vals[tq][r] : -FLT_MAX;
      mmax = fmaxf(mmax, vals[tq][r]);
    }
  }
  mmax = fmaxf(mmax, __shfl_xor(mmax, 16, 64));
  mmax = fmaxf(mmax, __shfl_xor(mmax, 32, 64));
  float esum = 0.f;
#pragma unroll
  for (int tq = 0; tq < 4; ++tq)
#pragma unroll
    for (int r = 0; r < 4; ++r) {
      vals[tq][r] = __expf(vals[tq][r] - mmax);
      esum += vals[tq][r];
    }
  esum += __shfl_xor(esum, 16, 64);
  esum += __shfl_xor(esum, 32, 64);
  float inv = 1.f / esum;
#pragma unroll
  for (int tq = 0; tq < 4; ++tq) {
    uint32_t p01 = packh2(vals[tq][0] * inv, vals[tq][1] * inv);
    uint32_t p23 = packh2(vals[tq][2] * inv, vals[tq][3] * inv);
    int qb4 = 16 * tq + 4 * lg;
    int phys = ((qb4 >> 3) ^ (lc & 7));
    char* dst = (char*)pbuf[wv] + lc * 128 + phys * 16 + (qb4 & 7) * 2;
    *(uint2*)dst = uint2{p01, p23};
  }
  f16x8 pfragB[2];
#pragma unroll
  for (int ks = 0; ks < 2; ++ks) {
    int phys = (lg + 4 * ks) ^ (lc & 7);
    U4H8 a; a.u = *(const uint4*)((const char*)pbuf[wv] + lc * 128 + phys * 16);
    pfragB[ks] = a.h;
  }
  const float* crow2 = ctx + ((size_t)b * C_ + c0w + lc) * D_;
  float* grow = g + ((size_t)b * C_ + c0w + lc) * (4 * D_);
#pragma unroll 4
  for (int dt = 0; dt < 16; ++dt) {
    f32x4 acc = f32x4{0.f, 0.f, 0.f, 0.f};
#pragma unroll
    for (int ks = 0; ks < 2; ++ks) {
      int d = dt * 16 + lc;
      int phys = (lg + 4 * ks) ^ (d & 7);
      U4H8 aq; aq.u = *(const uint4*)((const char*)qT + d * 128 + phys * 16);
      acc = __builtin_amdgcn_mfma_f32_16x16x32_f16(aq.h, pfragB[ks], acc, 0, 0, 0);
    }
    int dcol = dt * 16 + 4 * lg;
    float4 cvv = *(const float4*)(crow2 + dcol);
    float4 c2qv{acc[0], acc[1], acc[2], acc[3]};
    *(float4*)(grow + D_ + dcol) = c2qv;
    float4 p2{cvv.x * c2qv.x, cvv.y * c2qv.y, cvv.z * c2qv.z, cvv.w * c2qv.w};
    *(float4*)(grow + 2 * D_ + dcol) = p2;
  }
}

// K4 (fallback): reduce partials -> q2c in LDS, stream g3.
__global__ __launch_bounds__(256) void k_g3q(const float* __restrict__ ctx,
                                             const float* __restrict__ part,
                                             float* __restrict__ g) {
  int b = blockIdx.x, ch = blockIdx.y, t = threadIdx.x;
  __shared__ float q2c_l[D_];
  float s = 0.f;
#pragma unroll
  for (int k = 0; k < 8; ++k) s += part[((size_t)b * 8 + k) * D_ + t];
  q2c_l[t] = s;
  __syncthreads();
  int d4 = t & 63;
  int ro = t >> 6;
  float4 qv = *(const float4*)(q2c_l + 4 * d4);
#pragma unroll 4
  for (int it = 0; it < 16; ++it) {
    int c = ch * 64 + it * 4 + ro;
    float4 cv = *(const float4*)(ctx + ((size_t)b * C_ + c) * D_ + 4 * d4);
    float4 o{cv.x * qv.x, cv.y * qv.y, cv.z * qv.z, cv.w * qv.w};
    *(float4*)(g + ((size_t)b * C_ + c) * (4 * D_) + 3 * D_ + 4 * d4) = o;
  }
}

extern "C" void kernel_launch(void* const* d_in, const int* in_sizes, int n_in,
                              void* d_out, int out_size, void* d_ws, size_t ws_size,
                              hipStream_t stream) {
  const float* ctx   = (const float*)d_in[0];
  const float* qst   = (const float*)d_in[1];
  const int*   cmask = (const int*)d_in[2];
  const int*   qmask = (const int*)d_in[3];
  const float* w     = (const float*)d_in[4];
  float* g  = (float*)d_out;
  float* ws = (float*)d_ws;

  float*    qwq      = ws;             // B*Q   = 4096 floats
  float*    simmax   = ws + 4096;      // B*C   = 32768
  float*    part     = ws + 36864;     // B*8*D = 131072
  uint32_t* qraw_img = (uint32_t*)(ws + 167936);   // 524288 u32 (2 MB)
  uint32_t* qT_img   = (uint32_t*)(ws + 692224);   // 524288 u32 (2 MB)
  ushort*   P_img    = (ushort*)(ws + 1216512);    // 2M ushorts (4 MB)
  const size_t need_bytes = (size_t)(1216512 + 1048576) * 4;  // ~9.06 MB

  if (ws_size >= need_bytes) {
    k_prepack<<<dim3(B_, 4), 256, 0, stream>>>(qst, w, qraw_img, qT_img, qwq);
    k_sim<<<dim3(512), 256, 0, stream>>>(ctx, qmask, w, qwq, qraw_img,
                                         P_img, simmax);
    k_q2c_bs<<<dim3(B_, 8), 256, 0, stream>>>(ctx, simmax, cmask, part);
    k_c2q<<<dim3(512), 256, 0, stream>>>(ctx, qT_img, P_img, part, g);
  } else {
    k_rowdot<<<dim3(B_ * Q_ / 4), 256, 0, stream>>>(qst, w + D_, qwq, B_ * Q_);
    k_main_fb<<<dim3(512), 256, 0, stream>>>(ctx, qst, qmask, w, qwq, g, simmax);
    k_q2c_bs<<<dim3(B_, 8), 256, 0, stream>>>(ctx, simmax, cmask, part);
    k_g3q<<<dim3(B_, 8), 256, 0, stream>>>(ctx, part, g);
  }
}

// Round 18
// 57.405 us; speedup vs baseline: 1.0753x; 1.0570x over previous
//
#include <hip/hip_runtime.h>
#include <hip/hip_bf16.h>
#include <float.h>

#define B_ 64
#define C_ 512
#define Q_ 64
#define D_ 256

typedef _Float16 f16x8 __attribute__((ext_vector_type(8)));
typedef float f32x4 __attribute__((ext_vector_type(4)));

union U4H8 { uint4 u; f16x8 h; };
union UH2 { _Float16 h[2]; uint32_t u; };

__device__ __forceinline__ uint32_t packh2(float a, float b) {
  UH2 v; v.h[0] = (_Float16)a; v.h[1] = (_Float16)b; return v.u;
}

__device__ __forceinline__ float wred_sum(float v) {
#pragma unroll
  for (int off = 32; off > 0; off >>= 1) v += __shfl_xor(v, off, 64);
  return v;
}
__device__ __forceinline__ float wred_max(float v) {
#pragma unroll
  for (int off = 32; off > 0; off >>= 1) v = fmaxf(v, __shfl_xor(v, off, 64));
  return v;
}

// ---------- fallback-only kernels (r14 path) ----------
__global__ __launch_bounds__(256) void k_rowdot(const float* __restrict__ src,
                                                const float* __restrict__ wgt,
                                                float* __restrict__ out, int nrows) {
  int wv = threadIdx.x >> 6, ln = threadIdx.x & 63;
  int row = blockIdx.x * 4 + wv;
  if (row >= nrows) return;
  float4 s4 = *(const float4*)(src + (size_t)row * D_ + 4 * ln);
  float4 w4 = *(const float4*)(wgt + 4 * ln);
  float p = s4.x * w4.x + s4.y * w4.y + s4.z * w4.z + s4.w * w4.w;
  p = wred_sum(p);
  if (ln == 0) out[row] = p;
}

// K0: prepack question into f16 images (qraw + qT layouts, XOR swizzle baked
// in) for linear global_load_lds staging; computes qwq. grid (B,4) x 256.
__global__ __launch_bounds__(256) void k_prepack(const float* __restrict__ qst,
                                                 const float* __restrict__ w,
                                                 uint32_t* __restrict__ qraw_img,
                                                 uint32_t* __restrict__ qT_img,
                                                 float* __restrict__ qwq) {
  const int b = blockIdx.x;
  const int sub = blockIdx.y;      // 0..3
  const int t = threadIdx.x;
  const float* qb = qst + (size_t)b * Q_ * D_;
#pragma unroll
  for (int it = 0; it < 8; ++it) {
    int idx = sub * 2048 + it * 256 + t;
    int q = idx >> 7, jp = idx & 127;
    float2 v = *(const float2*)(qb + q * D_ + 2 * jp);
    int ch = jp >> 2;
    int phys = (ch & ~7) | ((ch & 7) ^ (q & 7));
    qraw_img[(size_t)b * 8192 + q * 128 + phys * 4 + (jp & 3)] = packh2(v.x, v.y);
  }
  {
    int d = sub * 64 + (t >> 2);
    uint32_t* dst = qT_img + (size_t)b * 8192 + d * 32;
#pragma unroll
    for (int k = 0; k < 2; ++k) {
      int qc = (t & 3) * 2 + k;
      uint32_t tmp[4];
#pragma unroll
      for (int e = 0; e < 4; ++e) {
        int q0 = qc * 8 + e * 2;
        tmp[e] = packh2(qb[q0 * D_ + d], qb[(q0 + 1) * D_ + d]);
      }
      int pc = qc ^ (d & 7);
      *(uint4*)(dst + pc * 4) = uint4{tmp[0], tmp[1], tmp[2], tmp[3]};
    }
  }
  if (sub == 0) {
    int q = t >> 2, sl = t & 3;
    float p = 0.f;
#pragma unroll
    for (int i = 0; i < 16; ++i) {
      float4 v = *(const float4*)(qb + q * D_ + sl * 64 + i * 4);
      float4 ww = *(const float4*)(w + D_ + sl * 64 + i * 4);
      p += v.x * ww.x + v.y * ww.y + v.z * ww.z + v.w * ww.w;
    }
    p += __shfl_xor(p, 1, 64);
    p += __shfl_xor(p, 2, 64);
    if (sl == 0) qwq[b * Q_ + q] = p;
  }
}

// KA: sim half + fused tile-local b-softmax partial (online two-level).
// LDS ~37.9 KB -> 4 blocks/CU. simT=mfma(qraw, ctx*wm); softmax_q; P->global
// image; then tile-local: M_loc/psum/pvec (weighted ctx sum, L1-hot re-read)
// -> part/pmax/psum partials. k_q2c_bs is DELETED (no full ctx re-read).
__global__ __launch_bounds__(256, 4) void k_sim(
    const float* __restrict__ ctx, const int* __restrict__ qmask,
    const int* __restrict__ cmask, const float* __restrict__ w,
    const float* __restrict__ qwq_g, const uint32_t* __restrict__ qraw_img,
    ushort* __restrict__ P_img, float* __restrict__ part,
    float* __restrict__ pmax_g, float* __restrict__ psum_g) {
  __shared__ __align__(16) ushort qraw[Q_ * D_];
  __shared__ float qwq_l[Q_];
  __shared__ int   qml_l[Q_];
  __shared__ __align__(16) float sred2[64];    // masked per-row max
  __shared__ float psum_w[4];
  __shared__ __align__(16) float pvLDS[4][256];

  const int bid = blockIdx.x;
  const int b = bid & 63;           // XCD-swizzle
  const int c0 = (bid >> 6) * 64;
  const int t = threadIdx.x;
  const int wv = t >> 6, ln = t & 63;
  const int lc = ln & 15;
  const int lg = ln >> 4;
  const int c0w = c0 + wv * 16;

  // ---- qraw image -> LDS (linear, width-16), issued first ----
  {
    const uint32_t* qr_src = qraw_img + (size_t)b * 8192;
#pragma unroll
    for (int i = 0; i < 8; ++i)
      __builtin_amdgcn_global_load_lds(
          (const __attribute__((address_space(1))) uint32_t*)(qr_src + i * 1024 + t * 4),
          (__attribute__((address_space(3))) uint32_t*)((uint32_t*)qraw + i * 1024 + t * 4),
          16, 0, 0);
  }

  // ---- B-frags: 16 ctx rows * w_m (f16) + fp32 cwc row-dot ----
  f16x8 bfrag[8];
  float cwc_p = 0.f;
  const float* crow = ctx + ((size_t)b * C_ + c0w + lc) * D_;
#pragma unroll
  for (int kk = 0; kk < 8; ++kk) {
    int kb = kk * 32 + lg * 8;
    float4 cv0 = *(const float4*)(crow + kb);
    float4 cv1 = *(const float4*)(crow + kb + 4);
    float4 wc0 = *(const float4*)(w + kb);
    float4 wc1 = *(const float4*)(w + kb + 4);
    float4 wm0 = *(const float4*)(w + 2 * D_ + kb);
    float4 wm1 = *(const float4*)(w + 2 * D_ + kb + 4);
    cwc_p += cv0.x * wc0.x + cv0.y * wc0.y + cv0.z * wc0.z + cv0.w * wc0.w
           + cv1.x * wc1.x + cv1.y * wc1.y + cv1.z * wc1.z + cv1.w * wc1.w;
    bfrag[kk][0] = (_Float16)(cv0.x * wm0.x);
    bfrag[kk][1] = (_Float16)(cv0.y * wm0.y);
    bfrag[kk][2] = (_Float16)(cv0.z * wm0.z);
    bfrag[kk][3] = (_Float16)(cv0.w * wm0.w);
    bfrag[kk][4] = (_Float16)(cv1.x * wm1.x);
    bfrag[kk][5] = (_Float16)(cv1.y * wm1.y);
    bfrag[kk][6] = (_Float16)(cv1.z * wm1.z);
    bfrag[kk][7] = (_Float16)(cv1.w * wm1.w);
  }
  float cwc = cwc_p;
  cwc += __shfl_xor(cwc, 16, 64);
  cwc += __shfl_xor(cwc, 32, 64);

  if (t < Q_) { qwq_l[t] = qwq_g[b * Q_ + t]; qml_l[t] = qmask[b * Q_ + t]; }
  __syncthreads();

  // ---- simT[q, c] via MFMA ----
  f32x4 sacc[4];
#pragma unroll
  for (int tq = 0; tq < 4; ++tq) sacc[tq] = f32x4{0.f, 0.f, 0.f, 0.f};
#pragma unroll
  for (int tq = 0; tq < 4; ++tq) {
    int q = 16 * tq + lc;
#pragma unroll
    for (int kk = 0; kk < 8; ++kk) {
      int ch = lg + 4 * kk;
      int phys = (ch & ~7) | ((ch & 7) ^ (q & 7));
      U4H8 a; a.u = *(const uint4*)((const char*)qraw + q * 512 + phys * 16);
      sacc[tq] = __builtin_amdgcn_mfma_f32_16x16x32_f16(a.h, bfrag[kk], sacc[tq], 0, 0, 0);
    }
  }

  // ---- softmax over q ----
  float vals[4][4];
  float rmax = -FLT_MAX;
#pragma unroll
  for (int tq = 0; tq < 4; ++tq) {
    float4 qw4 = *(const float4*)(qwq_l + 16 * tq + 4 * lg);
#pragma unroll
    for (int r = 0; r < 4; ++r) {
      float qv = (r == 0) ? qw4.x : (r == 1) ? qw4.y : (r == 2) ? qw4.z : qw4.w;
      vals[tq][r] = sacc[tq][r] + cwc + qv;
      rmax = fmaxf(rmax, vals[tq][r]);
    }
  }
  rmax = fmaxf(rmax, __shfl_xor(rmax, 16, 64));
  rmax = fmaxf(rmax, __shfl_xor(rmax, 32, 64));   // unmasked row max (ref)

  float mmax = -FLT_MAX;
#pragma unroll
  for (int tq = 0; tq < 4; ++tq) {
    int4 qm4 = *(const int4*)(qml_l + 16 * tq + 4 * lg);
#pragma unroll
    for (int r = 0; r < 4; ++r) {
      int m = (r == 0) ? qm4.x : (r == 1) ? qm4.y : (r == 2) ? qm4.z : qm4.w;
      vals[tq][r] = m ? vals[tq][r] : -FLT_MAX;
      mmax = fmaxf(mmax, vals[tq][r]);
    }
  }
  mmax = fmaxf(mmax, __shfl_xor(mmax, 16, 64));
  mmax = fmaxf(mmax, __shfl_xor(mmax, 32, 64));
  float esum = 0.f;
#pragma unroll
  for (int tq = 0; tq < 4; ++tq)
#pragma unroll
    for (int r = 0; r < 4; ++r) {
      vals[tq][r] = __expf(vals[tq][r] - mmax);      // masked -> exp(-huge) = 0
      esum += vals[tq][r];
    }
  esum += __shfl_xor(esum, 16, 64);
  esum += __shfl_xor(esum, 32, 64);
  float inv = 1.f / esum;
  // ---- P -> linear global image [c(16 rows x 128B)][q] per (bid, wave) ----
  char* pdst = (char*)(P_img + ((size_t)bid * 4 + wv) * 1024);
#pragma unroll
  for (int tq = 0; tq < 4; ++tq) {
    uint32_t p01 = packh2(vals[tq][0] * inv, vals[tq][1] * inv);
    uint32_t p23 = packh2(vals[tq][2] * inv, vals[tq][3] * inv);
    int qb4 = 16 * tq + 4 * lg;
    *(uint2*)(pdst + lc * 128 + qb4 * 2) = uint2{p01, p23};
  }

  // ---- fused tile-local b-softmax partial: M_loc, psum, pvec ----
  // mv = cmask ? rmax : -inf (ref: mask applied to the unmasked row max)
  if (ln < 16) {
    int cm = cmask[b * C_ + c0w + lc];
    sred2[wv * 16 + lc] = cm ? rmax : -FLT_MAX;
  }
  __syncthreads();
  float M_loc = -FLT_MAX;
#pragma unroll
  for (int i = 0; i < 16; ++i) {
    float4 v4 = *(const float4*)(sred2 + 4 * i);
    M_loc = fmaxf(M_loc, fmaxf(fmaxf(v4.x, v4.y), fmaxf(v4.z, v4.w)));
  }
  // wave handles its 16 rows (L1-hot), thread covers d = 4*ln..4*ln+3
  float4 pvec{0.f, 0.f, 0.f, 0.f};
  float ps = 0.f;
  const float* cbase = ctx + ((size_t)b * C_ + c0w) * D_ + 4 * ln;
#pragma unroll 4
  for (int r = 0; r < 16; ++r) {
    float e = __expf(sred2[wv * 16 + r] - M_loc);  // all-masked tile -> e=1,
    ps += e;                                       // killed by rescale in KB
    float4 cv = *(const float4*)(cbase + r * D_);
    pvec.x += e * cv.x; pvec.y += e * cv.y;
    pvec.z += e * cv.z; pvec.w += e * cv.w;
  }
  *(float4*)(&pvLDS[wv][4 * ln]) = pvec;
  if (ln == 0) psum_w[wv] = ps;
  __syncthreads();
  {
    float s = pvLDS[0][t] + pvLDS[1][t] + pvLDS[2][t] + pvLDS[3][t];
    part[((size_t)b * 8 + (bid >> 6)) * D_ + t] = s;
  }
  if (t == 0) {
    pmax_g[b * 8 + (bid >> 6)] = M_loc;
    psum_g[b * 8 + (bid >> 6)] = psum_w[0] + psum_w[1] + psum_w[2] + psum_w[3];
  }
}

// KB: c2q half. LDS = 32K(qT) + 1K(q2c) -> 4 blocks/CU.
// qT via global_load_lds; pfragB direct from P_img; q2c from the 8
// rescaled tile-partials (fixed order, deterministic); epilogue g0..g3.
__global__ __launch_bounds__(256, 4) void k_c2q(
    const float* __restrict__ ctx, const uint32_t* __restrict__ qT_img,
    const ushort* __restrict__ P_img, const float* __restrict__ part,
    const float* __restrict__ pmax_g, const float* __restrict__ psum_g,
    float* __restrict__ g) {
  __shared__ __align__(16) ushort qT[D_ * Q_];
  __shared__ float q2c_l[D_];

  const int bid = blockIdx.x;
  const int b = bid & 63;
  const int c0 = (bid >> 6) * 64;
  const int t = threadIdx.x;
  const int wv = t >> 6, ln = t & 63;
  const int lc = ln & 15;
  const int lg = ln >> 4;
  const int c0w = c0 + wv * 16;

  // ---- qT image -> LDS (linear, width-16) ----
  {
    const uint32_t* qt_src = qT_img + (size_t)b * 8192;
#pragma unroll
    for (int i = 0; i < 8; ++i)
      __builtin_amdgcn_global_load_lds(
          (const __attribute__((address_space(1))) uint32_t*)(qt_src + i * 1024 + t * 4),
          (__attribute__((address_space(3))) uint32_t*)((uint32_t*)qT + i * 1024 + t * 4),
          16, 0, 0);
  }
  // ---- pfragB: direct global reads (linear [c][q] image) ----
  const char* psrc = (const char*)(P_img + ((size_t)bid * 4 + wv) * 1024);
  U4H8 pf0, pf1;
  pf0.u = *(const uint4*)(psrc + lc * 128 + lg * 16);        // ks=0
  pf1.u = *(const uint4*)(psrc + lc * 128 + lg * 16 + 64);   // ks=1
  // ---- q2c from rescaled tile-partials (fixed order) ----
  {
    float M = -FLT_MAX;
#pragma unroll
    for (int k = 0; k < 8; ++k) M = fmaxf(M, pmax_g[b * 8 + k]);
    float den = 0.f, num = 0.f;
#pragma unroll
    for (int k = 0; k < 8; ++k) {
      float sc = __expf(pmax_g[b * 8 + k] - M);
      den += psum_g[b * 8 + k] * sc;
      num += part[((size_t)b * 8 + k) * D_ + t] * sc;
    }
    q2c_l[t] = num / den;
  }
  __syncthreads();   // drains qT loads + q2c writes

  // ---- c2qT[d, c] via MFMA + full epilogue ----
  const float* crow2 = ctx + ((size_t)b * C_ + c0w + lc) * D_;
  float* grow = g + ((size_t)b * C_ + c0w + lc) * (4 * D_);
#pragma unroll 4
  for (int dt = 0; dt < 16; ++dt) {
    f32x4 acc = f32x4{0.f, 0.f, 0.f, 0.f};
    {
      int d = dt * 16 + lc;
      int phys0 = lg ^ (d & 7);
      int phys1 = (lg + 4) ^ (d & 7);
      U4H8 aq0; aq0.u = *(const uint4*)((const char*)qT + d * 128 + phys0 * 16);
      U4H8 aq1; aq1.u = *(const uint4*)((const char*)qT + d * 128 + phys1 * 16);
      acc = __builtin_amdgcn_mfma_f32_16x16x32_f16(aq0.h, pf0.h, acc, 0, 0, 0);
      acc = __builtin_amdgcn_mfma_f32_16x16x32_f16(aq1.h, pf1.h, acc, 0, 0, 0);
    }
    int dcol = dt * 16 + 4 * lg;
    float4 cvv = *(const float4*)(crow2 + dcol);
    float4 q4 = *(const float4*)(q2c_l + dcol);
    *(float4*)(grow + dcol) = cvv;                             // g[0:D] = ctx
    float4 c2qv{acc[0], acc[1], acc[2], acc[3]};
    *(float4*)(grow + D_ + dcol) = c2qv;                       // g[D:2D] = c2q
    float4 p2{cvv.x * c2qv.x, cvv.y * c2qv.y, cvv.z * c2qv.z, cvv.w * c2qv.w};
    *(float4*)(grow + 2 * D_ + dcol) = p2;                     // g[2D:3D]
    float4 p3{cvv.x * q4.x, cvv.y * q4.y, cvv.z * q4.z, cvv.w * q4.w};
    *(float4*)(grow + 3 * D_ + dcol) = p3;                     // g[3D:4D]
  }
}

// ---------- fallback path (r14) ----------
__global__ __launch_bounds__(256) void k_q2c_bs(const float* __restrict__ ctx,
                                                const float* __restrict__ simmax,
                                                const int* __restrict__ cmask,
                                                float* __restrict__ part) {
  int b = blockIdx.x, ch = blockIdx.y, t = threadIdx.x;
  int wv = t >> 6, ln = t & 63;
  __shared__ float bls[C_];
  __shared__ float sred[4];
  __shared__ float ssum[4];
  float v0 = simmax[b * C_ + t], v1 = simmax[b * C_ + 256 + t];
  if (!cmask[b * C_ + t]) v0 = -FLT_MAX;
  if (!cmask[b * C_ + 256 + t]) v1 = -FLT_MAX;
  float mx = wred_max(fmaxf(v0, v1));
  if (ln == 0) sred[wv] = mx;
  __syncthreads();
  float bm = fmaxf(fmaxf(sred[0], sred[1]), fmaxf(sred[2], sred[3]));
  float e0 = __expf(v0 - bm), e1 = __expf(v1 - bm);
  float ps = wred_sum(e0 + e1);
  if (ln == 0) ssum[wv] = ps;
  __syncthreads();
  float bs = ssum[0] + ssum[1] + ssum[2] + ssum[3];
  float invbs = 1.f / bs;
  bls[t] = e0 * invbs;
  bls[256 + t] = e1 * invbs;
  __syncthreads();
  float acc = 0.f;
  int cbeg = ch * 64;
#pragma unroll 4
  for (int c = cbeg; c < cbeg + 64; ++c)
    acc += bls[c] * ctx[((size_t)b * C_ + c) * D_ + t];
  part[((size_t)b * 8 + ch) * D_ + t] = acc;
}

__global__ __launch_bounds__(256, 2) void k_main_fb(
    const float* __restrict__ ctx, const float* __restrict__ qst,
    const int* __restrict__ qmask, const float* __restrict__ w,
    const float* __restrict__ qwq_g, float* __restrict__ g,
    float* __restrict__ simmax_g) {
  __shared__ __align__(16) ushort qraw[Q_ * D_];
  __shared__ __align__(16) ushort qT[D_ * Q_];
  __shared__ __align__(16) ushort pbuf[4][16 * Q_];
  __shared__ float qwq_l[Q_];
  __shared__ int   qml_l[Q_];

  const int bid = blockIdx.x;
  const int b = bid & 63;
  const int c0 = (bid >> 6) * 64;
  const int t = threadIdx.x;
  const int wv = t >> 6, ln = t & 63;
  const int lc = ln & 15;
  const int lg = ln >> 4;
  const int c0w = c0 + wv * 16;
  const float* qb = qst + (size_t)b * Q_ * D_;

  f16x8 bfrag[8];
  float cwc_p = 0.f;
  const float* crow = ctx + ((size_t)b * C_ + c0w + lc) * D_;
  float* grow0 = g + ((size_t)b * C_ + c0w + lc) * (4 * D_);
#pragma unroll
  for (int kk = 0; kk < 8; ++kk) {
    int kb = kk * 32 + lg * 8;
    float4 cv0 = *(const float4*)(crow + kb);
    float4 cv1 = *(const float4*)(crow + kb + 4);
    float4 wc0 = *(const float4*)(w + kb);
    float4 wc1 = *(const float4*)(w + kb + 4);
    float4 wm0 = *(const float4*)(w + 2 * D_ + kb);
    float4 wm1 = *(const float4*)(w + 2 * D_ + kb + 4);
    cwc_p += cv0.x * wc0.x + cv0.y * wc0.y + cv0.z * wc0.z + cv0.w * wc0.w
           + cv1.x * wc1.x + cv1.y * wc1.y + cv1.z * wc1.z + cv1.w * wc1.w;
    bfrag[kk][0] = (_Float16)(cv0.x * wm0.x);
    bfrag[kk][1] = (_Float16)(cv0.y * wm0.y);
    bfrag[kk][2] = (_Float16)(cv0.z * wm0.z);
    bfrag[kk][3] = (_Float16)(cv0.w * wm0.w);
    bfrag[kk][4] = (_Float16)(cv1.x * wm1.x);
    bfrag[kk][5] = (_Float16)(cv1.y * wm1.y);
    bfrag[kk][6] = (_Float16)(cv1.z * wm1.z);
    bfrag[kk][7] = (_Float16)(cv1.w * wm1.w);
    *(float4*)(grow0 + kb) = cv0;
    *(float4*)(grow0 + kb + 4) = cv1;
  }
  float cwc = cwc_p;
  cwc += __shfl_xor(cwc, 16, 64);
  cwc += __shfl_xor(cwc, 32, 64);

#pragma unroll 4
  for (int it = 0; it < 32; ++it) {
    int idx = it * 256 + t;
    int q = idx >> 7, jp = idx & 127;
    float2 v = *(const float2*)(qb + q * D_ + 2 * jp);
    int ch = jp >> 2;
    int phys = (ch & ~7) | ((ch & 7) ^ (q & 7));
    *(uint32_t*)((char*)qraw + q * 512 + phys * 16 + (jp & 3) * 4) = packh2(v.x, v.y);
  }
#pragma unroll 4
  for (int it = 0; it < 32; ++it) {
    int q = t & 63;
    int jp = (t >> 6) + 4 * it;
    float2 v = *(const float2*)(qb + q * D_ + 2 * jp);
    int d0 = 2 * jp, d1 = d0 + 1;
    UH2 h0; h0.h[0] = (_Float16)v.x;
    UH2 h1; h1.h[0] = (_Float16)v.y;
    *(ushort*)((char*)qT + d0 * 128 + (((q >> 3) ^ (d0 & 7)) << 4) + (q & 7) * 2) = (ushort)(h0.u & 0xffff);
    *(ushort*)((char*)qT + d1 * 128 + (((q >> 3) ^ (d1 & 7)) << 4) + (q & 7) * 2) = (ushort)(h1.u & 0xffff);
  }
  if (t < Q_) { qwq_l[t] = qwq_g[b * Q_ + t]; qml_l[t] = qmask[b * Q_ + t]; }
  __syncthreads();

  f32x4 sacc[4];
#pragma unroll
  for (int tq = 0; tq < 4; ++tq) sacc[tq] = f32x4{0.f, 0.f, 0.f, 0.f};
#pragma unroll
  for (int tq = 0; tq < 4; ++tq) {
    int q = 16 * tq + lc;
#pragma unroll
    for (int kk = 0; kk < 8; ++kk) {
      int ch = lg + 4 * kk;
      int phys = (ch & ~7) | ((ch & 7) ^ (q & 7));
      U4H8 a; a.u = *(const uint4*)((const char*)qraw + q * 512 + phys * 16);
      sacc[tq] = __builtin_amdgcn_mfma_f32_16x16x32_f16(a.h, bfrag[kk], sacc[tq], 0, 0, 0);
    }
  }
  float vals[4][4];
  float rmax = -FLT_MAX;
#pragma unroll
  for (int tq = 0; tq < 4; ++tq) {
    float4 qw4 = *(const float4*)(qwq_l + 16 * tq + 4 * lg);
#pragma unroll
    for (int r = 0; r < 4; ++r) {
      float qv = (r == 0) ? qw4.x : (r == 1) ? qw4.y : (r == 2) ? qw4.z : qw4.w;
      vals[tq][r] = sacc[tq][r] + cwc + qv;
      rmax = fmaxf(rmax, vals[tq][r]);
    }
  }
  rmax = fmaxf(rmax, __shfl_xor(rmax, 16, 64));
  rmax = fmaxf(rmax, __shfl_xor(rmax, 32, 64));
  if (ln < 16) simmax_g[b * C_ + c0w + lc] = rmax;
  float mmax = -FLT_MAX;
#pragma unroll
  for (int tq = 0; tq < 4; ++tq) {
    int4 qm4 = *(const int4*)(qml_l + 16 * tq + 4 * lg);
#pragma unroll
    for (int r = 0; r < 4; ++r) {
      int m = (r == 0) ? qm4.x : (r == 1) ? qm4.y : (r == 2) ? qm4.z : qm4.w;
      vals[tq][r] = m ? vals[tq][r] : -FLT_MAX;
      mmax = fmaxf(mmax, vals[tq][r]);
    }
  }
  mmax = fmaxf(mmax, __shfl_xor(mmax, 16, 64));
  mmax = fmaxf(mmax, __shfl_xor(mmax, 32, 64));
  float esum = 0.f;
#pragma unroll
  for (int tq = 0; tq < 4; ++tq)
#pragma unroll
    for (int r = 0; r < 4; ++r) {
      vals[tq][r] = __expf(vals[tq][r] - mmax);
      esum += vals[tq][r];
    }
  esum += __shfl_xor(esum, 16, 64);
  esum += __shfl_xor(esum, 32, 64);
  float inv = 1.f / esum;
#pragma unroll
  for (int tq = 0; tq < 4; ++tq) {
    uint32_t p01 = packh2(vals[tq][0] * inv, vals[tq][1] * inv);
    uint32_t p23 = packh2(vals[tq][2] * inv, vals[tq][3] * inv);
    int qb4 = 16 * tq + 4 * lg;
    int phys = ((qb4 >> 3) ^ (lc & 7));
    char* dst = (char*)pbuf[wv] + lc * 128 + phys * 16 + (qb4 & 7) * 2;
    *(uint2*)dst = uint2{p01, p23};
  }
  f16x8 pfragB[2];
#pragma unroll
  for (int ks = 0; ks < 2; ++ks) {
    int phys = (lg + 4 * ks) ^ (lc & 7);
    U4H8 a; a.u = *(const uint4*)((const char*)pbuf[wv] + lc * 128 + phys * 16);
    pfragB[ks] = a.h;
  }
  const float* crow2 = ctx + ((size_t)b * C_ + c0w + lc) * D_;
  float* grow = g + ((size_t)b * C_ + c0w + lc) * (4 * D_);
#pragma unroll 4
  for (int dt = 0; dt < 16; ++dt) {
    f32x4 acc = f32x4{0.f, 0.f, 0.f, 0.f};
#pragma unroll
    for (int ks = 0; ks < 2; ++ks) {
      int d = dt * 16 + lc;
      int phys = (lg + 4 * ks) ^ (d & 7);
      U4H8 aq; aq.u = *(const uint4*)((const char*)qT + d * 128 + phys * 16);
      acc = __builtin_amdgcn_mfma_f32_16x16x32_f16(aq.h, pfragB[ks], acc, 0, 0, 0);
    }
    int dcol = dt * 16 + 4 * lg;
    float4 cvv = *(const float4*)(crow2 + dcol);
    float4 c2qv{acc[0], acc[1], acc[2], acc[3]};
    *(float4*)(grow + D_ + dcol) = c2qv;
    float4 p2{cvv.x * c2qv.x, cvv.y * c2qv.y, cvv.z * c2qv.z, cvv.w * c2qv.w};
    *(float4*)(grow + 2 * D_ + dcol) = p2;
  }
}

__global__ __launch_bounds__(256) void k_g3q(const float* __restrict__ ctx,
                                             const float* __restrict__ part,
                                             float* __restrict__ g) {
  int b = blockIdx.x, ch = blockIdx.y, t = threadIdx.x;
  __shared__ float q2c_l[D_];
  float s = 0.f;
#pragma unroll
  for (int k = 0; k < 8; ++k) s += part[((size_t)b * 8 + k) * D_ + t];
  q2c_l[t] = s;
  __syncthreads();
  int d4 = t & 63;
  int ro = t >> 6;
  float4 qv = *(const float4*)(q2c_l + 4 * d4);
#pragma unroll 4
  for (int it = 0; it < 16; ++it) {
    int c = ch * 64 + it * 4 + ro;
    float4 cv = *(const float4*)(ctx + ((size_t)b * C_ + c) * D_ + 4 * d4);
    float4 o{cv.x * qv.x, cv.y * qv.y, cv.z * qv.z, cv.w * qv.w};
    *(float4*)(g + ((size_t)b * C_ + c) * (4 * D_) + 3 * D_ + 4 * d4) = o;
  }
}

extern "C" void kernel_launch(void* const* d_in, const int* in_sizes, int n_in,
                              void* d_out, int out_size, void* d_ws, size_t ws_size,
                              hipStream_t stream) {
  const float* ctx   = (const float*)d_in[0];
  const float* qst   = (const float*)d_in[1];
  const int*   cmask = (const int*)d_in[2];
  const int*   qmask = (const int*)d_in[3];
  const float* w     = (const float*)d_in[4];
  float* g  = (float*)d_out;
  float* ws = (float*)d_ws;

  // layout (floats): qwq[0,4096) simmax[4096,36864) part[36864,167936)
  //   pmax[167936,168448) psum[168448,168960) | imgs after (r17 overlap FIXED)
  float*    qwq      = ws;
  float*    simmax   = ws + 4096;                  // fallback only
  float*    part     = ws + 36864;                 // B*8*D = 131072 floats
  float*    pmax_g   = ws + 167936;                // 512
  float*    psum_g   = ws + 168448;                // 512
  uint32_t* qraw_img = (uint32_t*)(ws + 168960);   // 524288 u32 (2 MB)
  uint32_t* qT_img   = (uint32_t*)(ws + 693248);   // 524288 u32 (2 MB)
  ushort*   P_img    = (ushort*)(ws + 1217536);    // 2M ushorts (4 MB)
  const size_t need_bytes = (size_t)(1217536 + 1048576) * 4;  // ~9.06 MB

  if (ws_size >= need_bytes) {
    k_prepack<<<dim3(B_, 4), 256, 0, stream>>>(qst, w, qraw_img, qT_img, qwq);
    k_sim<<<dim3(512), 256, 0, stream>>>(ctx, qmask, cmask, w, qwq, qraw_img,
                                         P_img, part, pmax_g, psum_g);
    k_c2q<<<dim3(512), 256, 0, stream>>>(ctx, qT_img, P_img, part,
                                         pmax_g, psum_g, g);
  } else {
    k_rowdot<<<dim3(B_ * Q_ / 4), 256, 0, stream>>>(qst, w + D_, qwq, B_ * Q_);
    k_main_fb<<<dim3(512), 256, 0, stream>>>(ctx, qst, qmask, w, qwq, g, simmax);
    k_q2c_bs<<<dim3(B_, 8), 256, 0, stream>>>(ctx, simmax, cmask, part);
    k_g3q<<<dim3(B_, 8), 256, 0, stream>>>(ctx, part, g);
  }
}